// Round 2
// baseline (57761.536 us; speedup 1.0000x reference)
//
#include <hip/hip_runtime.h>
#include <hip/hip_bf16.h>

#define SEQ    200
#define BATCH  128
#define NHID   1024
#define NDEPTH 5
#define NBLK   256   // persistent blocks == CUs
#define CPB    4     // hidden columns owned per block

typedef __bf16 bf16x8 __attribute__((ext_vector_type(8)));
typedef float  f32x4  __attribute__((ext_vector_type(4)));
typedef __hip_bfloat16 bf16_t;

__device__ __forceinline__ f32x4 mfma16(bf16x8 a, bf16x8 b, f32x4 c) {
    return __builtin_amdgcn_mfma_f32_16x16x32_bf16(a, b, c, 0, 0, 0);
}

__global__ void k_prep_xm(const float* __restrict__ inp, const float* __restrict__ h_mask,
                          bf16_t* __restrict__ xm, int n) {
    for (int i = blockIdx.x * blockDim.x + threadIdx.x; i < n; i += gridDim.x * blockDim.x) {
        int r = i & (BATCH * NHID - 1);
        xm[i] = __float2bfloat16(inp[i] * h_mask[r]);
    }
}

__global__ void k_init_smb(const float* __restrict__ hidden, const float* __restrict__ s_mask,
                           bf16_t* __restrict__ smb, int n) {
    for (int i = blockIdx.x * blockDim.x + threadIdx.x; i < n; i += gridDim.x * blockDim.x)
        smb[i] = __float2bfloat16(hidden[i] * s_mask[i]);
}

// Persistent RHN kernel. 256 blocks x 256 threads; block b owns hidden cols [4b, 4b+4).
// LDS holds this block's weight slice for ALL matrices, packed as 6 regions of 8 rows:
//   region m=0: rows 0-3 = Wih[c0+r], rows 4-7 = Wit[c0+r-4]      (layer-0 input pair)
//   region m=1+l: rows 0-3 = Wh[l][c0+r], rows 4-7 = Wt[l][c0+r-4]
// Each wave computes 2 row-tiles (16 rows each) x one packed 16-col MFMA tile
// (cols 0-3 = H-gate, 4-7 = T-gate, 8-15 duplicate / ignored).
__global__ __launch_bounds__(256, 1) void k_rhn_persist(
    const float* __restrict__ hidden, const float* __restrict__ s_mask,
    const float* __restrict__ Wih, const float* __restrict__ bih,
    const float* __restrict__ Wit, const float* __restrict__ bitv,
    const float* __restrict__ Wh,  const float* __restrict__ bh,
    const float* __restrict__ Wt,  const float* __restrict__ bt,
    const bf16_t* __restrict__ xm,
    bf16_t* __restrict__ smbA, bf16_t* __restrict__ smbB,
    unsigned int* __restrict__ cnt, float* __restrict__ out)
{
    extern __shared__ bf16_t wlds[];   // 48 rows x NHID bf16 = 96 KB
    const int tid  = threadIdx.x;
    const int lane = tid & 63;
    const int wv   = tid >> 6;
    const int c0   = blockIdx.x * CPB;

    // ---- stage weight slice f32 -> bf16 LDS (once) ----
    for (int row_id = wv; row_id < 48; row_id += 4) {
        const int m = row_id >> 3, r = row_id & 7;
        const int c = c0 + (r & 3);
        const float* src;
        if (m == 0) src = ((r < 4) ? Wih : Wit) + (size_t)c * NHID;
        else        src = ((r < 4) ? Wh  : Wt ) + ((size_t)(m - 1) * NHID + c) * NHID;
        bf16_t* dst = wlds + (size_t)row_id * NHID;
        const int e = lane * 16;
        #pragma unroll
        for (int u = 0; u < 16; ++u)
            dst[e + u] = __float2bfloat16(src[e + u]);
    }

    // ---- per-lane roles & register state ----
    const int lr = lane & 15;          // MFMA fragment row / C col index
    const int kg = lane >> 4;          // k-group
    const int wbase = wv * 32;         // batch-row base of this wave
    const int cc = c0 + (lr & 3);      // hidden column this lane's role refers to
    const bool isT = (lr & 4) != 0;

    float biasl[NDEPTH];
    #pragma unroll
    for (int l = 0; l < NDEPTH; ++l) {
        float bb = isT ? bt[(size_t)l * NHID + cc] : bh[(size_t)l * NHID + cc];
        if (l == 0) bb += isT ? bitv[cc] : bih[cc];
        biasl[l] = bb;
    }

    float sreg[2][4], smk[2][4];
    #pragma unroll
    for (int tile = 0; tile < 2; ++tile)
        #pragma unroll
        for (int j = 0; j < 4; ++j) {
            const int row = wbase + tile * 16 + kg * 4 + j;
            sreg[tile][j] = hidden[(size_t)row * NHID + cc];
            smk[tile][j]  = s_mask[(size_t)row * NHID + cc];
        }

    __syncthreads();   // LDS weights ready

    const size_t aoff0 = (size_t)(wbase + lr) * NHID + kg * 8;
    const size_t aoff1 = aoff0 + (size_t)16 * NHID;
    unsigned int target = 0;
    int par = 0;

    for (int t = 0; t < SEQ; ++t) {
        const bf16_t* xmt = xm + (size_t)t * BATCH * NHID;
        #pragma unroll
        for (int l = 0; l < NDEPTH; ++l) {
            const bf16_t* A  = par ? smbB : smbA;
            bf16_t*       An = par ? smbA : smbB;
            f32x4 acc0 = {0.f, 0.f, 0.f, 0.f}, acc1 = {0.f, 0.f, 0.f, 0.f};
            {   // recurrent path: sm @ [Wh_l | Wt_l]^T
                const bf16_t* wl = wlds + ((size_t)(1 + l) * 8 + (lane & 7)) * NHID + kg * 8;
                const bf16_t* a0 = A + aoff0;
                const bf16_t* a1 = A + aoff1;
                #pragma unroll 4
                for (int k = 0; k < NHID; k += 32) {
                    bf16x8 bfrag = *(const bf16x8*)(wl + k);
                    bf16x8 af0   = *(const bf16x8*)(a0 + k);
                    bf16x8 af1   = *(const bf16x8*)(a1 + k);
                    acc0 = mfma16(af0, bfrag, acc0);
                    acc1 = mfma16(af1, bfrag, acc1);
                }
            }
            if (l == 0) {   // input path folded in: x_t @ [Wih | Wit]^T
                const bf16_t* wl = wlds + (size_t)(lane & 7) * NHID + kg * 8;
                const bf16_t* a0 = xmt + aoff0;
                const bf16_t* a1 = xmt + aoff1;
                #pragma unroll 4
                for (int k = 0; k < NHID; k += 32) {
                    bf16x8 bfrag = *(const bf16x8*)(wl + k);
                    bf16x8 af0   = *(const bf16x8*)(a0 + k);
                    bf16x8 af1   = *(const bf16x8*)(a1 + k);
                    acc0 = mfma16(af0, bfrag, acc0);
                    acc1 = mfma16(af1, bfrag, acc1);
                }
            }

            // ---- epilogue: C col = lane&15, row = (lane>>4)*4 + j ----
            const float vb = biasl[l];
            #pragma unroll
            for (int tile = 0; tile < 2; ++tile) {
                #pragma unroll
                for (int j = 0; j < 4; ++j) {
                    float v = (tile == 0 ? acc0[j] : acc1[j]) + vb;
                    // swap H<->T pre-activations across lane XOR 4 (within 32-lane groups)
                    float o = __int_as_float(
                        __builtin_amdgcn_ds_swizzle(__float_as_int(v), 0x101F));
                    float Hv = tanhf(v);                      // valid on H-lanes
                    float Tv = 1.f / (1.f + __expf(-o));      // o = T-pre on H-lanes
                    float sv = sreg[tile][j];
                    float sn = (Hv - sv) * Tv + sv;
                    sreg[tile][j] = sn;
                    if (lr < 4) {
                        const int row = wbase + tile * 16 + kg * 4 + j;
                        An[(size_t)row * NHID + cc] = __float2bfloat16(sn * smk[tile][j]);
                        if (l == NDEPTH - 1) {
                            out[((size_t)t * BATCH + row) * NHID + cc] = sn;
                            if (t == SEQ - 1)
                                out[(size_t)SEQ * BATCH * NHID + (size_t)row * NHID + cc] = sn;
                        }
                    }
                }
            }

            // ---- device-wide barrier (monotonic counter, agent-scope fences) ----
            __threadfence();          // release: drain this thread's stores
            __syncthreads();          // whole block done writing
            target += NBLK;
            if (tid == 0) {
                __hip_atomic_fetch_add(cnt, 1u, __ATOMIC_RELEASE, __HIP_MEMORY_SCOPE_AGENT);
                while (__hip_atomic_load(cnt, __ATOMIC_RELAXED, __HIP_MEMORY_SCOPE_AGENT) < target)
                    __builtin_amdgcn_s_sleep(1);
            }
            __syncthreads();          // block waits for observer
            __threadfence();          // acquire: invalidate stale cache lines
            par ^= 1;
        }
    }
}

extern "C" void kernel_launch(void* const* d_in, const int* in_sizes, int n_in,
                              void* d_out, int out_size, void* d_ws, size_t ws_size,
                              hipStream_t stream) {
    (void)in_sizes; (void)n_in; (void)out_size; (void)ws_size;

    const float* inp    = (const float*)d_in[0];
    const float* hidden = (const float*)d_in[1];
    const float* h_mask = (const float*)d_in[2];
    const float* s_mask = (const float*)d_in[3];
    const float* Wih    = (const float*)d_in[4];
    const float* bih    = (const float*)d_in[5];
    const float* Wit    = (const float*)d_in[6];
    const float* bitv   = (const float*)d_in[7];
    const float* Wh     = (const float*)d_in[8];
    const float* bh     = (const float*)d_in[9];
    const float* Wt     = (const float*)d_in[10];
    const float* bt     = (const float*)d_in[11];
    float* out = (float*)d_out;

    // ws layout: xm (bf16, 52.4MB) | smbA | smbB | counter
    bf16_t* xm   = (bf16_t*)d_ws;
    bf16_t* smbA = xm + (size_t)SEQ * BATCH * NHID;
    bf16_t* smbB = smbA + (size_t)BATCH * NHID;
    unsigned int* cnt = (unsigned int*)(smbB + (size_t)BATCH * NHID);

    hipMemsetAsync(cnt, 0, sizeof(unsigned int), stream);
    k_prep_xm<<<dim3(2048), dim3(256), 0, stream>>>(inp, h_mask, xm, SEQ * BATCH * NHID);
    k_init_smb<<<dim3(64), dim3(256), 0, stream>>>(hidden, s_mask, smbA, BATCH * NHID);

    const size_t ldsBytes = (size_t)48 * NHID * sizeof(bf16_t);  // 96 KB
    hipFuncSetAttribute((const void*)k_rhn_persist,
                        hipFuncAttributeMaxDynamicSharedMemorySize, (int)ldsBytes);
    k_rhn_persist<<<dim3(NBLK), dim3(256), ldsBytes, stream>>>(
        hidden, s_mask, Wih, bih, Wit, bitv, Wh, bh, Wt, bt,
        xm, smbA, smbB, cnt, out);
}

// Round 3
// 51242.389 us; speedup vs baseline: 1.1272x; 1.1272x over previous
//
#include <hip/hip_runtime.h>
#include <hip/hip_bf16.h>

#define SEQ    200
#define BATCH  128
#define NHID   1024
#define NDEPTH 5
#define NBLK   256        // persistent blocks == CUs
#define CPB    4          // hidden columns owned per block
#define WSTRIDE (NHID + 16)   // LDS row stride in bf16: bank base = 8r+4kg mod 32 -> 2-way max

typedef __bf16 bf16x8 __attribute__((ext_vector_type(8)));
typedef float  f32x4  __attribute__((ext_vector_type(4)));
typedef __hip_bfloat16 bf16_t;

__device__ __forceinline__ f32x4 mfma16(bf16x8 a, bf16x8 b, f32x4 c) {
    return __builtin_amdgcn_mfma_f32_16x16x32_bf16(a, b, c, 0, 0, 0);
}

__global__ void k_prep_xm(const float* __restrict__ inp, const float* __restrict__ h_mask,
                          bf16_t* __restrict__ xm, int n) {
    for (int i = blockIdx.x * blockDim.x + threadIdx.x; i < n; i += gridDim.x * blockDim.x) {
        int r = i & (BATCH * NHID - 1);
        xm[i] = __float2bfloat16(inp[i] * h_mask[r]);
    }
}

__global__ void k_init_smb(const float* __restrict__ hidden, const float* __restrict__ s_mask,
                           bf16_t* __restrict__ smb, int n) {
    for (int i = blockIdx.x * blockDim.x + threadIdx.x; i < n; i += gridDim.x * blockDim.x)
        smb[i] = __float2bfloat16(hidden[i] * s_mask[i]);
}

__global__ __launch_bounds__(256, 1) void k_rhn_persist(
    const float* __restrict__ hidden, const float* __restrict__ s_mask,
    const float* __restrict__ Wih, const float* __restrict__ bih,
    const float* __restrict__ Wit, const float* __restrict__ bitv,
    const float* __restrict__ Wh,  const float* __restrict__ bh,
    const float* __restrict__ Wt,  const float* __restrict__ bt,
    const bf16_t* __restrict__ xm,
    bf16_t* __restrict__ smbA, bf16_t* __restrict__ smbB,
    unsigned int* __restrict__ flags,   // 256 slots, 16 uints (64B) apart
    unsigned int* __restrict__ go,      // single release word
    float* __restrict__ out)
{
    extern __shared__ bf16_t wlds[];   // 48 rows x WSTRIDE bf16 = 97.5 KB
    const int tid  = threadIdx.x;
    const int lane = tid & 63;
    const int wv   = tid >> 6;
    const int c0   = blockIdx.x * CPB;

    // ---- stage weight slice f32 -> bf16 LDS (once) ----
    for (int row_id = wv; row_id < 48; row_id += 4) {
        const int m = row_id >> 3, r = row_id & 7;
        const int c = c0 + (r & 3);
        const float* src;
        if (m == 0) src = ((r < 4) ? Wih : Wit) + (size_t)c * NHID;
        else        src = ((r < 4) ? Wh  : Wt ) + ((size_t)(m - 1) * NHID + c) * NHID;
        bf16_t* dst = wlds + (size_t)row_id * WSTRIDE;
        const int e = lane * 16;
        #pragma unroll
        for (int u = 0; u < 16; ++u)
            dst[e + u] = __float2bfloat16(src[e + u]);
    }

    // ---- per-lane roles & register state ----
    const int lr = lane & 15;
    const int kg = lane >> 4;
    const int wbase = wv * 32;
    const int cc = c0 + (lr & 3);
    const bool isT = (lr & 4) != 0;

    float biasl[NDEPTH];
    #pragma unroll
    for (int l = 0; l < NDEPTH; ++l) {
        float bb = isT ? bt[(size_t)l * NHID + cc] : bh[(size_t)l * NHID + cc];
        if (l == 0) bb += isT ? bitv[cc] : bih[cc];
        biasl[l] = bb;
    }

    float sreg[2][4], smk[2][4];
    #pragma unroll
    for (int tile = 0; tile < 2; ++tile)
        #pragma unroll
        for (int j = 0; j < 4; ++j) {
            const int row = wbase + tile * 16 + kg * 4 + j;
            sreg[tile][j] = hidden[(size_t)row * NHID + cc];
            smk[tile][j]  = s_mask[(size_t)row * NHID + cc];
        }

    __syncthreads();   // LDS weights ready

    const size_t aoff0 = (size_t)(wbase + lr) * NHID + kg * 8;
    const size_t aoff1 = aoff0 + (size_t)16 * NHID;
    unsigned int round = 0;
    int par = 0;

    for (int t = 0; t < SEQ; ++t) {
        const bf16_t* xmt = xm + (size_t)t * BATCH * NHID;
        #pragma unroll
        for (int l = 0; l < NDEPTH; ++l) {
            const bf16_t* A  = par ? smbB : smbA;
            bf16_t*       An = par ? smbA : smbB;
            f32x4 acc0 = {0.f, 0.f, 0.f, 0.f}, acc1 = {0.f, 0.f, 0.f, 0.f};
            {   // recurrent path: sm @ [Wh_l | Wt_l]^T
                const bf16_t* wl = wlds + (size_t)((1 + l) * 8 + (lane & 7)) * WSTRIDE + kg * 8;
                const bf16_t* a0 = A + aoff0;
                const bf16_t* a1 = A + aoff1;
                #pragma unroll 4
                for (int k = 0; k < NHID; k += 32) {
                    bf16x8 bfrag = *(const bf16x8*)(wl + k);
                    bf16x8 af0   = *(const bf16x8*)(a0 + k);
                    bf16x8 af1   = *(const bf16x8*)(a1 + k);
                    acc0 = mfma16(af0, bfrag, acc0);
                    acc1 = mfma16(af1, bfrag, acc1);
                }
            }
            if (l == 0) {   // input path folded in: x_t @ [Wih | Wit]^T
                const bf16_t* wl = wlds + (size_t)(lane & 7) * WSTRIDE + kg * 8;
                const bf16_t* a0 = xmt + aoff0;
                const bf16_t* a1 = xmt + aoff1;
                #pragma unroll 4
                for (int k = 0; k < NHID; k += 32) {
                    bf16x8 bfrag = *(const bf16x8*)(wl + k);
                    bf16x8 af0   = *(const bf16x8*)(a0 + k);
                    bf16x8 af1   = *(const bf16x8*)(a1 + k);
                    acc0 = mfma16(af0, bfrag, acc0);
                    acc1 = mfma16(af1, bfrag, acc1);
                }
            }

            // ---- epilogue: C col = lane&15, row = (lane>>4)*4 + j ----
            const float vb = biasl[l];
            #pragma unroll
            for (int tile = 0; tile < 2; ++tile) {
                #pragma unroll
                for (int j = 0; j < 4; ++j) {
                    float v = (tile == 0 ? acc0[j] : acc1[j]) + vb;
                    float o = __int_as_float(
                        __builtin_amdgcn_ds_swizzle(__float_as_int(v), 0x101F)); // lane^4: H<->T
                    float Hv = tanhf(v);
                    float Tv = 1.f / (1.f + __expf(-o));
                    float sv = sreg[tile][j];
                    float sn = (Hv - sv) * Tv + sv;
                    sreg[tile][j] = sn;
                    if (lr < 4) {
                        const int row = wbase + tile * 16 + kg * 4 + j;
                        An[(size_t)row * NHID + cc] = __float2bfloat16(sn * smk[tile][j]);
                        if (l == NDEPTH - 1) {
                            out[((size_t)t * BATCH + row) * NHID + cc] = sn;
                            if (t == SEQ - 1)
                                out[(size_t)SEQ * BATCH * NHID + (size_t)row * NHID + cc] = sn;
                        }
                    }
                }
            }

            // ---- device-wide barrier: distributed flags + master + go broadcast ----
            ++round;
            __threadfence();                 // release: drain/flush this thread's stores
            __syncthreads();                 // whole block done writing + fenced
            if (tid == 0)
                __hip_atomic_store(&flags[blockIdx.x * 16], round,
                                   __ATOMIC_RELEASE, __HIP_MEMORY_SCOPE_AGENT);
            if (blockIdx.x == 0) {
                // master: 256 threads each watch one block's flag (1 reader per line)
                while (__hip_atomic_load(&flags[tid * 16],
                                         __ATOMIC_RELAXED, __HIP_MEMORY_SCOPE_AGENT) < round)
                    __builtin_amdgcn_s_sleep(1);
                __syncthreads();             // all flags observed
                if (tid == 0)
                    __hip_atomic_store(go, round,
                                       __ATOMIC_RELEASE, __HIP_MEMORY_SCOPE_AGENT);
            } else {
                if (tid == 0) {
                    while (__hip_atomic_load(go,
                                             __ATOMIC_RELAXED, __HIP_MEMORY_SCOPE_AGENT) < round)
                        __builtin_amdgcn_s_sleep(2);
                }
                __syncthreads();             // block waits on observer thread
            }
            __threadfence();                 // acquire: invalidate stale cached smb
            par ^= 1;
        }
    }
}

extern "C" void kernel_launch(void* const* d_in, const int* in_sizes, int n_in,
                              void* d_out, int out_size, void* d_ws, size_t ws_size,
                              hipStream_t stream) {
    (void)in_sizes; (void)n_in; (void)out_size; (void)ws_size;

    const float* inp    = (const float*)d_in[0];
    const float* hidden = (const float*)d_in[1];
    const float* h_mask = (const float*)d_in[2];
    const float* s_mask = (const float*)d_in[3];
    const float* Wih    = (const float*)d_in[4];
    const float* bih    = (const float*)d_in[5];
    const float* Wit    = (const float*)d_in[6];
    const float* bitv   = (const float*)d_in[7];
    const float* Wh     = (const float*)d_in[8];
    const float* bh     = (const float*)d_in[9];
    const float* Wt     = (const float*)d_in[10];
    const float* bt     = (const float*)d_in[11];
    float* out = (float*)d_out;

    // ws layout: xm (bf16, 52.4MB) | smbA | smbB | flags (16KB) | go
    bf16_t* xm   = (bf16_t*)d_ws;
    bf16_t* smbA = xm + (size_t)SEQ * BATCH * NHID;
    bf16_t* smbB = smbA + (size_t)BATCH * NHID;
    unsigned int* flags = (unsigned int*)(smbB + (size_t)BATCH * NHID);
    unsigned int* go    = flags + NBLK * 16;

    hipMemsetAsync(flags, 0, (NBLK * 16 + 16) * sizeof(unsigned int), stream);
    k_prep_xm<<<dim3(2048), dim3(256), 0, stream>>>(inp, h_mask, xm, SEQ * BATCH * NHID);
    k_init_smb<<<dim3(64), dim3(256), 0, stream>>>(hidden, s_mask, smbA, BATCH * NHID);

    const size_t ldsBytes = (size_t)48 * WSTRIDE * sizeof(bf16_t);  // 97.5 KB
    hipFuncSetAttribute((const void*)k_rhn_persist,
                        hipFuncAttributeMaxDynamicSharedMemorySize, (int)ldsBytes);
    k_rhn_persist<<<dim3(NBLK), dim3(256), ldsBytes, stream>>>(
        hidden, s_mask, Wih, bih, Wit, bitv, Wh, bh, Wt, bt,
        xm, smbA, smbB, flags, go, out);
}

// Round 4
// 20189.813 us; speedup vs baseline: 2.8609x; 2.5380x over previous
//
#include <hip/hip_runtime.h>
#include <hip/hip_bf16.h>
#include <stdint.h>

#define SEQ    200
#define BATCH  128
#define NHID   1024
#define NDEPTH 5
#define NBLK   256            // persistent blocks == CUs
#define CPB    4              // hidden columns owned per block
#define WSTRIDE (NHID + 16)   // LDS row stride (bf16): breaks power-of-2 bank aliasing

typedef __bf16 bf16x8 __attribute__((ext_vector_type(8)));
typedef float  f32x4  __attribute__((ext_vector_type(4)));
typedef __hip_bfloat16 bf16_t;

__device__ __forceinline__ f32x4 mfma16(bf16x8 a, bf16x8 b, f32x4 c) {
    return __builtin_amdgcn_mfma_f32_16x16x32_bf16(a, b, c, 0, 0, 0);
}

__device__ __forceinline__ unsigned short f32_to_bf16_bits(float f) {
    uint32_t x = __float_as_uint(f);
    uint32_t r = ((x >> 16) & 1u) + 0x7fffu;   // round-to-nearest-even
    return (unsigned short)((x + r) >> 16);
}

__global__ void k_prep_xm(const float* __restrict__ inp, const float* __restrict__ h_mask,
                          bf16_t* __restrict__ xm, int n) {
    for (int i = blockIdx.x * blockDim.x + threadIdx.x; i < n; i += gridDim.x * blockDim.x) {
        int r = i & (BATCH * NHID - 1);
        xm[i] = __float2bfloat16(inp[i] * h_mask[r]);
    }
}

__global__ void k_init_smb(const float* __restrict__ hidden, const float* __restrict__ s_mask,
                           bf16_t* __restrict__ smb, int n) {
    for (int i = blockIdx.x * blockDim.x + threadIdx.x; i < n; i += gridDim.x * blockDim.x)
        smb[i] = __float2bfloat16(hidden[i] * s_mask[i]);
}

// Persistent RHN. 256 blocks x 512 threads (8 waves). Block b owns hidden cols [4b,4b+4).
// Wave w owns batch rows [16w, 16w+16). LDS holds this block's bf16 weight slice
// (6 regions x 8 rows: region 0 = Wih|Wit, region 1+l = Wh[l]|Wt[l]).
// Cross-block state exchange via sc0/sc1 (agent-scope relaxed atomic) stores+loads:
// no threadfence / no L2 writeback-invalidate anywhere in the main loop.
__global__ __launch_bounds__(512, 2) void k_rhn_persist(
    const float* __restrict__ hidden, const float* __restrict__ s_mask,
    const float* __restrict__ Wih, const float* __restrict__ bih,
    const float* __restrict__ Wit, const float* __restrict__ bitv,
    const float* __restrict__ Wh,  const float* __restrict__ bh,
    const float* __restrict__ Wt,  const float* __restrict__ bt,
    const bf16_t* __restrict__ xm,
    bf16_t* __restrict__ smbA, bf16_t* __restrict__ smbB,
    unsigned int* __restrict__ flags,   // 256 slots, 64B apart
    unsigned int* __restrict__ go,
    float* __restrict__ out)
{
    extern __shared__ bf16_t wlds[];   // 48 x WSTRIDE bf16 = 97.5 KB
    const int tid  = threadIdx.x;
    const int lane = tid & 63;
    const int wv   = tid >> 6;          // 0..7
    const int c0   = blockIdx.x * CPB;

    // ---- stage weight slice f32 -> bf16 LDS (once) ----
    for (int row_id = wv; row_id < 48; row_id += 8) {
        const int m = row_id >> 3, r = row_id & 7;
        const int c = c0 + (r & 3);
        const float* src;
        if (m == 0) src = ((r < 4) ? Wih : Wit) + (size_t)c * NHID;
        else        src = ((r < 4) ? Wh  : Wt ) + ((size_t)(m - 1) * NHID + c) * NHID;
        bf16_t* dst = wlds + (size_t)row_id * WSTRIDE;
        const int e = lane * 16;
        #pragma unroll
        for (int u = 0; u < 16; ++u)
            dst[e + u] = __float2bfloat16(src[e + u]);
    }

    // ---- per-lane roles & register state ----
    const int lr = lane & 15;
    const int kg = lane >> 4;
    const int wbase = wv * 16;          // 16 batch rows per wave
    const int cc = c0 + (lr & 3);
    const bool isT = (lr & 4) != 0;

    float biasl[NDEPTH];
    #pragma unroll
    for (int l = 0; l < NDEPTH; ++l) {
        float bb = isT ? bt[(size_t)l * NHID + cc] : bh[(size_t)l * NHID + cc];
        if (l == 0) bb += isT ? bitv[cc] : bih[cc];
        biasl[l] = bb;
    }

    float sreg[4], smk[4];
    #pragma unroll
    for (int j = 0; j < 4; ++j) {
        const int row = wbase + kg * 4 + j;
        sreg[j] = hidden[(size_t)row * NHID + cc];
        smk[j]  = s_mask[(size_t)row * NHID + cc];
    }

    __syncthreads();   // LDS weights ready

    unsigned int round = 0;
    int par = 0;

    for (int t = 0; t < SEQ; ++t) {
        const bf16_t* xmt = xm + (size_t)t * BATCH * NHID;
        #pragma unroll
        for (int l = 0; l < NDEPTH; ++l) {
            const bf16_t* Abuf = par ? smbB : smbA;
            bf16_t*       An   = par ? smbA : smbB;
            f32x4 acc = {0.f, 0.f, 0.f, 0.f};

            {   // recurrent path: sm @ [Wh_l | Wt_l]^T ; A via sc1 loads (cross-XCD fresh)
                const uint64_t* Ar =
                    (const uint64_t*)(Abuf + (size_t)(wbase + lr) * NHID + kg * 8);
                const bf16_t* wl = wlds + (size_t)((1 + l) * 8 + (lane & 7)) * WSTRIDE + kg * 8;
                #pragma unroll 8
                for (int kk = 0; kk < 32; ++kk) {
                    uint64_t lo = __hip_atomic_load(Ar + (size_t)kk * 8,
                                    __ATOMIC_RELAXED, __HIP_MEMORY_SCOPE_AGENT);
                    uint64_t hi = __hip_atomic_load(Ar + (size_t)kk * 8 + 1,
                                    __ATOMIC_RELAXED, __HIP_MEMORY_SCOPE_AGENT);
                    union { uint64_t u[2]; bf16x8 v; } cv;
                    cv.u[0] = lo; cv.u[1] = hi;
                    bf16x8 bfrag = *(const bf16x8*)(wl + kk * 32);
                    acc = mfma16(cv.v, bfrag, acc);
                }
            }
            if (l == 0) {   // input path folded in: x_t @ [Wih | Wit]^T (read-only, cached)
                const bf16_t* xr = xmt + (size_t)(wbase + lr) * NHID + kg * 8;
                const bf16_t* wl = wlds + (size_t)(lane & 7) * WSTRIDE + kg * 8;
                #pragma unroll 8
                for (int kk = 0; kk < 32; ++kk) {
                    bf16x8 af    = *(const bf16x8*)(xr + kk * 32);
                    bf16x8 bfrag = *(const bf16x8*)(wl + kk * 32);
                    acc = mfma16(af, bfrag, acc);
                }
            }

            // ---- epilogue: C col = lane&15, row = (lane>>4)*4 + j ----
            const float vb = biasl[l];
            #pragma unroll
            for (int j = 0; j < 4; ++j) {
                float v = acc[j] + vb;
                float o = __int_as_float(
                    __builtin_amdgcn_ds_swizzle(__float_as_int(v), 0x101F)); // lane^4: H<->T
                float Hv = tanhf(v);
                float Tv = 1.f / (1.f + __expf(-o));
                float sv = sreg[j];
                float sn = (Hv - sv) * Tv + sv;
                sreg[j] = sn;
                if (lr < 4) {
                    const int row = wbase + kg * 4 + j;
                    unsigned short bits = f32_to_bf16_bits(sn * smk[j]);
                    __hip_atomic_store((unsigned short*)(An + (size_t)row * NHID + cc), bits,
                                       __ATOMIC_RELAXED, __HIP_MEMORY_SCOPE_AGENT);
                    if (l == NDEPTH - 1) {
                        __hip_atomic_store(&out[((size_t)t * BATCH + row) * NHID + cc], sn,
                                           __ATOMIC_RELAXED, __HIP_MEMORY_SCOPE_AGENT);
                        if (t == SEQ - 1)
                            __hip_atomic_store(&out[(size_t)SEQ * BATCH * NHID
                                                    + (size_t)row * NHID + cc], sn,
                                               __ATOMIC_RELAXED, __HIP_MEMORY_SCOPE_AGENT);
                    }
                }
            }

            // ---- device-wide barrier: flags -> master -> go (no cache flushes) ----
            ++round;
            __syncthreads();   // implies s_waitcnt vmcnt(0): block's sc1 stores are acked
            if (tid == 0)
                __hip_atomic_store(&flags[blockIdx.x * 16], round,
                                   __ATOMIC_RELEASE, __HIP_MEMORY_SCOPE_AGENT);
            if (blockIdx.x == 0) {
                if (tid < NBLK)
                    while (__hip_atomic_load(&flags[tid * 16],
                                             __ATOMIC_RELAXED, __HIP_MEMORY_SCOPE_AGENT) < round)
                        __builtin_amdgcn_s_sleep(1);
                __syncthreads();
                if (tid == 0)
                    __hip_atomic_store(go, round,
                                       __ATOMIC_RELEASE, __HIP_MEMORY_SCOPE_AGENT);
            } else {
                if (tid == 0)
                    while (__hip_atomic_load(go,
                                             __ATOMIC_RELAXED, __HIP_MEMORY_SCOPE_AGENT) < round)
                        __builtin_amdgcn_s_sleep(2);
                __syncthreads();
            }
            par ^= 1;
        }
    }
}

extern "C" void kernel_launch(void* const* d_in, const int* in_sizes, int n_in,
                              void* d_out, int out_size, void* d_ws, size_t ws_size,
                              hipStream_t stream) {
    (void)in_sizes; (void)n_in; (void)out_size; (void)ws_size;

    const float* inp    = (const float*)d_in[0];
    const float* hidden = (const float*)d_in[1];
    const float* h_mask = (const float*)d_in[2];
    const float* s_mask = (const float*)d_in[3];
    const float* Wih    = (const float*)d_in[4];
    const float* bih    = (const float*)d_in[5];
    const float* Wit    = (const float*)d_in[6];
    const float* bitv   = (const float*)d_in[7];
    const float* Wh     = (const float*)d_in[8];
    const float* bh     = (const float*)d_in[9];
    const float* Wt     = (const float*)d_in[10];
    const float* bt     = (const float*)d_in[11];
    float* out = (float*)d_out;

    // ws layout: xm (bf16, 52.4MB) | smbA | smbB | flags | go
    bf16_t* xm   = (bf16_t*)d_ws;
    bf16_t* smbA = xm + (size_t)SEQ * BATCH * NHID;
    bf16_t* smbB = smbA + (size_t)BATCH * NHID;
    unsigned int* flags = (unsigned int*)(smbB + (size_t)BATCH * NHID);
    unsigned int* go    = flags + NBLK * 16;

    hipMemsetAsync(flags, 0, (NBLK * 16 + 16) * sizeof(unsigned int), stream);
    k_prep_xm<<<dim3(2048), dim3(256), 0, stream>>>(inp, h_mask, xm, SEQ * BATCH * NHID);
    k_init_smb<<<dim3(64), dim3(256), 0, stream>>>(hidden, s_mask, smbA, BATCH * NHID);

    const size_t ldsBytes = (size_t)48 * WSTRIDE * sizeof(bf16_t);  // 97.5 KB
    hipFuncSetAttribute((const void*)k_rhn_persist,
                        hipFuncAttributeMaxDynamicSharedMemorySize, (int)ldsBytes);
    k_rhn_persist<<<dim3(NBLK), dim3(512), ldsBytes, stream>>>(
        hidden, s_mask, Wih, bih, Wit, bitv, Wh, bh, Wt, bt,
        xm, smbA, smbB, flags, go, out);
}

// Round 6
// 11270.174 us; speedup vs baseline: 5.1252x; 1.7914x over previous
//
#include <hip/hip_runtime.h>
#include <hip/hip_bf16.h>
#include <stdint.h>

#define SEQ    200
#define BATCH  128
#define NHID   1024
#define NDEPTH 5
#define NBLK   256            // persistent blocks == CUs
#define CPB    4              // hidden columns owned per block
#define WSTRIDE (NHID + 16)   // LDS row stride (bf16): breaks power-of-2 bank aliasing
#define NGO    32             // replicated go lines

typedef __bf16 bf16x8 __attribute__((ext_vector_type(8)));
typedef float  f32x4  __attribute__((ext_vector_type(4)));
typedef uint32_t u32x4 __attribute__((ext_vector_type(4)));
typedef __hip_bfloat16 bf16_t;

__device__ __forceinline__ f32x4 mfma16(bf16x8 a, bf16x8 b, f32x4 c) {
    return __builtin_amdgcn_mfma_f32_16x16x32_bf16(a, b, c, 0, 0, 0);
}
__device__ __forceinline__ bf16x8 as_bf16x8(u32x4 x) {
    union { u32x4 u; bf16x8 b; } t; t.u = x; return t.b;
}
__device__ __forceinline__ unsigned short f32_to_bf16_bits(float f) {
    uint32_t x = __float_as_uint(f);
    uint32_t r = ((x >> 16) & 1u) + 0x7fffu;   // RNE
    return (unsigned short)((x + r) >> 16);
}

__global__ void k_prep_xm(const float* __restrict__ inp, const float* __restrict__ h_mask,
                          bf16_t* __restrict__ xm, int n) {
    for (int i = blockIdx.x * blockDim.x + threadIdx.x; i < n; i += gridDim.x * blockDim.x) {
        int r = i & (BATCH * NHID - 1);
        xm[i] = __float2bfloat16(inp[i] * h_mask[r]);
    }
}

__global__ void k_init_smb(const float* __restrict__ hidden, const float* __restrict__ s_mask,
                           bf16_t* __restrict__ smb, int n) {
    for (int i = blockIdx.x * blockDim.x + threadIdx.x; i < n; i += gridDim.x * blockDim.x)
        smb[i] = __float2bfloat16(hidden[i] * s_mask[i]);
}

// batched A loads: sc0 sc1 (coherence-point) for smb, plain cached for xm
#define LDU(i, OFF) asm volatile("global_load_dwordx4 %0, %1, off offset:" OFF " sc0 sc1" \
                                 : "=v"(AR[i]) : "v"(aptr));
#define LDCQ(i, OFF) asm volatile("global_load_dwordx4 %0, %1, off offset:" OFF \
                                 : "=v"(AR[i]) : "v"(xptr));
#define ISSUE32(M) \
    M(0,"0")    M(1,"64")   M(2,"128")  M(3,"192")  M(4,"256")  M(5,"320")  M(6,"384")  M(7,"448") \
    M(8,"512")  M(9,"576")  M(10,"640") M(11,"704") M(12,"768") M(13,"832") M(14,"896") M(15,"960") \
    M(16,"1024") M(17,"1088") M(18,"1152") M(19,"1216") M(20,"1280") M(21,"1344") M(22,"1408") M(23,"1472") \
    M(24,"1536") M(25,"1600") M(26,"1664") M(27,"1728") M(28,"1792") M(29,"1856") M(30,"1920") M(31,"1984")
// MFMA must not hoist above the wait; ALU/SALU/DS may (0x1|0x2|0x4|0x80|0x100)
#define WAITV(N) do { asm volatile("s_waitcnt vmcnt(" #N ")" ::: "memory"); \
                      __builtin_amdgcn_sched_barrier(0x187); } while (0)
#define CHUNK(c) do { _Pragma("unroll") \
    for (int e = 0; e < 8; ++e) { \
        bf16x8 bfrag = *(const bf16x8*)(wl + ((c) * 8 + e) * 32); \
        acc = mfma16(as_bf16x8(AR[(c) * 8 + e]), bfrag, acc); } } while (0)

__global__ __launch_bounds__(512, 2) void k_rhn_persist(
    const float* __restrict__ hidden, const float* __restrict__ s_mask,
    const float* __restrict__ Wih, const float* __restrict__ bih,
    const float* __restrict__ Wit, const float* __restrict__ bitv,
    const float* __restrict__ Wh,  const float* __restrict__ bh,
    const float* __restrict__ Wt,  const float* __restrict__ bt,
    const bf16_t* __restrict__ xm,
    bf16_t* __restrict__ smbA, bf16_t* __restrict__ smbB,
    unsigned int* __restrict__ flags,   // 256 slots, 64B apart
    unsigned int* __restrict__ goarr,   // 32 slots, 64B apart
    float* __restrict__ out)
{
    extern __shared__ bf16_t wlds[];   // 48 x WSTRIDE bf16 = 97.5 KB
    const int tid  = threadIdx.x;
    const int lane = tid & 63;
    const int wv   = tid >> 6;          // 0..7
    const int c0   = blockIdx.x * CPB;

    // ---- stage weight slice f32 -> bf16 LDS (once) ----
    for (int row_id = wv; row_id < 48; row_id += 8) {
        const int m = row_id >> 3, r = row_id & 7;
        const int c = c0 + (r & 3);
        const float* src;
        if (m == 0) src = ((r < 4) ? Wih : Wit) + (size_t)c * NHID;
        else        src = ((r < 4) ? Wh  : Wt ) + ((size_t)(m - 1) * NHID + c) * NHID;
        bf16_t* dst = wlds + (size_t)row_id * WSTRIDE;
        const int e = lane * 16;
        #pragma unroll
        for (int u = 0; u < 16; ++u)
            dst[e + u] = __float2bfloat16(src[e + u]);
    }

    // ---- per-lane roles & register state ----
    const int lr = lane & 15;
    const int kg = lane >> 4;
    const int wbase = wv * 16;          // 16 batch rows per wave
    const int cc = c0 + (lr & 3);
    const bool isT = (lr & 4) != 0;

    float biasl[NDEPTH];
    #pragma unroll
    for (int l = 0; l < NDEPTH; ++l) {
        float bb = isT ? bt[(size_t)l * NHID + cc] : bh[(size_t)l * NHID + cc];
        if (l == 0) bb += isT ? bitv[cc] : bih[cc];
        biasl[l] = bb;
    }

    float sreg[4], smk[4];
    #pragma unroll
    for (int j = 0; j < 4; ++j) {
        const int row = wbase + kg * 4 + j;
        sreg[j] = hidden[(size_t)row * NHID + cc];
        smk[j]  = s_mask[(size_t)row * NHID + cc];
    }

    __syncthreads();   // LDS weights ready

    const size_t aoff = (size_t)(wbase + lr) * NHID + kg * 8;
    unsigned int round = 0;
    int par = 0;

    for (int t = 0; t < SEQ; ++t) {
        const bf16_t* xmt = xm + (size_t)t * BATCH * NHID;
        #pragma unroll
        for (int l = 0; l < NDEPTH; ++l) {
            const bf16_t* Abuf = par ? smbB : smbA;
            bf16_t*       An   = par ? smbA : smbB;
            f32x4 acc = {0.f, 0.f, 0.f, 0.f};
            u32x4 AR[32];

            {   // recurrent path: sm @ [Wh_l | Wt_l]^T  — 32 coherent b128 loads in flight
                const bf16_t* aptr = Abuf + aoff;
                const bf16_t* wl = wlds + (size_t)((1 + l) * 8 + (lane & 7)) * WSTRIDE + kg * 8;
                ISSUE32(LDU)
                WAITV(24); CHUNK(0);
                WAITV(16); CHUNK(1);
                WAITV(8);  CHUNK(2);
                WAITV(0);  CHUNK(3);
            }
            if (l == 0) {   // input path folded in: x_t @ [Wih | Wit]^T (cached loads)
                const bf16_t* xptr = xmt + aoff;
                const bf16_t* wl = wlds + (size_t)(lane & 7) * WSTRIDE + kg * 8;
                ISSUE32(LDCQ)
                WAITV(24); CHUNK(0);
                WAITV(16); CHUNK(1);
                WAITV(8);  CHUNK(2);
                WAITV(0);  CHUNK(3);
            }

            // ---- epilogue: C col = lane&15, row = (lane>>4)*4 + j ----
            const float vb = biasl[l];
            #pragma unroll
            for (int j = 0; j < 4; ++j) {
                float v = acc[j] + vb;
                float o = __int_as_float(
                    __builtin_amdgcn_ds_swizzle(__float_as_int(v), 0x101F)); // lane^4: H<->T
                float Hv = tanhf(v);
                float Tv = 1.f / (1.f + __expf(-o));
                float sv = sreg[j];
                float sn = (Hv - sv) * Tv + sv;
                sreg[j] = sn;
                const int row = wbase + kg * 4 + j;

                // pack 4 cols x bf16 (lanes lr=0..3) into one 8B store from lane lr==0
                uint32_t a  = (uint32_t)f32_to_bf16_bits(sn * smk[j]);
                uint32_t b  = __builtin_amdgcn_ds_swizzle(a, 0x041F);   // lane^1
                uint32_t w  = (a & 0xffffu) | (b << 16);
                uint32_t c2 = __builtin_amdgcn_ds_swizzle(w, 0x081F);   // lane^2
                if (lr == 0) {
                    uint64_t q = (uint64_t)w | ((uint64_t)c2 << 32);
                    __hip_atomic_store((uint64_t*)(An + (size_t)row * NHID + c0), q,
                                       __ATOMIC_RELAXED, __HIP_MEMORY_SCOPE_AGENT);
                }
                if (l == NDEPTH - 1 && lr < 4) {     // out: plain cached stores
                    out[((size_t)t * BATCH + row) * NHID + cc] = sn;
                    if (t == SEQ - 1)
                        out[(size_t)SEQ * BATCH * NHID + (size_t)row * NHID + cc] = sn;
                }
            }

            // ---- device-wide barrier: flags -> master -> replicated go ----
            ++round;
            __syncthreads();   // emits s_waitcnt vmcnt(0): block's stores acked at L3
            if (tid == 0)
                __hip_atomic_store(&flags[blockIdx.x * 16], round,
                                   __ATOMIC_RELAXED, __HIP_MEMORY_SCOPE_AGENT);
            if (blockIdx.x == 0) {
                if (tid < NBLK)
                    while (__hip_atomic_load(&flags[tid * 16],
                                             __ATOMIC_RELAXED, __HIP_MEMORY_SCOPE_AGENT) < round)
                        __builtin_amdgcn_s_sleep(2);
                __syncthreads();
                if (tid < NGO)
                    __hip_atomic_store(&goarr[tid * 16], round,
                                       __ATOMIC_RELAXED, __HIP_MEMORY_SCOPE_AGENT);
            } else {
                if (tid == 0)
                    while (__hip_atomic_load(&goarr[(blockIdx.x & (NGO - 1)) * 16],
                                             __ATOMIC_RELAXED, __HIP_MEMORY_SCOPE_AGENT) < round)
                        __builtin_amdgcn_s_sleep(2);
                __syncthreads();
            }
            par ^= 1;
        }
    }
}

extern "C" void kernel_launch(void* const* d_in, const int* in_sizes, int n_in,
                              void* d_out, int out_size, void* d_ws, size_t ws_size,
                              hipStream_t stream) {
    (void)in_sizes; (void)n_in; (void)out_size; (void)ws_size;

    const float* inp    = (const float*)d_in[0];
    const float* hidden = (const float*)d_in[1];
    const float* h_mask = (const float*)d_in[2];
    const float* s_mask = (const float*)d_in[3];
    const float* Wih    = (const float*)d_in[4];
    const float* bih    = (const float*)d_in[5];
    const float* Wit    = (const float*)d_in[6];
    const float* bitv   = (const float*)d_in[7];
    const float* Wh     = (const float*)d_in[8];
    const float* bh     = (const float*)d_in[9];
    const float* Wt     = (const float*)d_in[10];
    const float* bt     = (const float*)d_in[11];
    float* out = (float*)d_out;

    // ws layout: xm (bf16, 52.4MB) | smbA | smbB | flags | goarr
    bf16_t* xm   = (bf16_t*)d_ws;
    bf16_t* smbA = xm + (size_t)SEQ * BATCH * NHID;
    bf16_t* smbB = smbA + (size_t)BATCH * NHID;
    unsigned int* flags = (unsigned int*)(smbB + (size_t)BATCH * NHID);
    unsigned int* goarr = flags + NBLK * 16;

    hipMemsetAsync(flags, 0, (NBLK * 16 + NGO * 16) * sizeof(unsigned int), stream);
    k_prep_xm<<<dim3(2048), dim3(256), 0, stream>>>(inp, h_mask, xm, SEQ * BATCH * NHID);
    k_init_smb<<<dim3(64), dim3(256), 0, stream>>>(hidden, s_mask, smbA, BATCH * NHID);

    const size_t ldsBytes = (size_t)48 * WSTRIDE * sizeof(bf16_t);  // 97.5 KB
    hipFuncSetAttribute((const void*)k_rhn_persist,
                        hipFuncAttributeMaxDynamicSharedMemorySize, (int)ldsBytes);
    k_rhn_persist<<<dim3(NBLK), dim3(512), ldsBytes, stream>>>(
        hidden, s_mask, Wih, bih, Wit, bitv, Wh, bh, Wt, bt,
        xm, smbA, smbB, flags, goarr, out);
}